// Round 14
// baseline (356.469 us; speedup 1.0000x reference)
//
#include <hip/hip_runtime.h>

#define NN 100000
#define FD 64
#define OUTF 2
#define NB 391        // ceil(NN/256) dst buckets, bucket = d >> 8
#define NBP 392       // padded ghist row stride
#define P1CH 4096     // edges per block in partition kernels
#define NTILE 6250    // NN/16 exactly
#define MLPB 782      // mlp grid blocks
#define GPSTR 800     // partial-array stride (>= MLPB)
#define BCAP 6016     // k_build LDS edge-buffer capacity (avg 4096, +30 sigma)

typedef short bf16x8 __attribute__((ext_vector_type(8), may_alias));
typedef float f32x4 __attribute__((ext_vector_type(4)));
typedef float f32x2 __attribute__((ext_vector_type(2)));

// bf16 helpers (round-to-nearest-even)
__device__ inline ushort f2bf(float f) {
    uint u = __float_as_uint(f);
    uint r = (u + 0x7FFFu + ((u >> 16) & 1u)) >> 16;
    return (ushort)r;
}
__device__ inline float bf2f(ushort v) {
    return __uint_as_float(((uint)v) << 16);
}

// ---------------- utility kernels ----------------

__global__ void k_zero(float* __restrict__ p, int n) {
    int i = blockIdx.x * blockDim.x + threadIdx.x;
    if (i < n) p[i] = 0.f;
}

__global__ void k_copy4(const float4* __restrict__ s, float4* __restrict__ d, int n4) {
    int i = blockIdx.x * blockDim.x + threadIdx.x;
    int st = gridDim.x * blockDim.x;
    for (; i < n4; i += st) d[i] = s[i];
}

// standalone cvt (fallback path only)
__global__ void k_cvt(const float4* __restrict__ x4, ushort4* __restrict__ xb4, int n4) {
    int i = blockIdx.x * blockDim.x + threadIdx.x;
    int st = gridDim.x * blockDim.x;
    for (; i < n4; i += st) {
        float4 v = x4[i];
        ushort4 w;
        w.x = f2bf(v.x);
        w.y = f2bf(v.y);
        w.z = f2bf(v.z);
        w.w = f2bf(v.w);
        xb4[i] = w;
    }
}

// ---------------- fused cvt + bucket histogram (role-split grid) ----------
// Blocks [0, np1): per-block LDS histogram of dst buckets -> ghist row.
// Blocks [np1, np1+2048): f32->bf16 cvt of x; block np1 also zeroes the
// sentinel zero-rows (index NN) of xb/h1b and the arrival counters.
__global__ __launch_bounds__(256) void k_cvt_hist(
        const int* __restrict__ ei, int* __restrict__ ghist, int E_, int np1,
        const float4* __restrict__ x4, ushort4* __restrict__ xb4,
        ushort* __restrict__ xb, ushort* __restrict__ h1b,
        int* __restrict__ ctrs, int n4) {
    __shared__ int h[NB];
    int tid = threadIdx.x;
    int blk = blockIdx.x;
    if (blk < np1) {
        for (int i = tid; i < NB; i += 256) h[i] = 0;
        __syncthreads();
        int c0 = blk * P1CH;
        int c1 = min(c0 + P1CH, E_);
        for (int i = c0 + tid; i < c1; i += 256) {
            int d = ei[E_ + i];
            int b = min(max(d >> 8, 0), NB - 1);
            atomicAdd(&h[b], 1);
        }
        __syncthreads();
        int* row = ghist + (size_t)blk * NBP;
        for (int i = tid; i < NB; i += 256) row[i] = h[i];
    } else {
        int bb = blk - np1;
        if (bb == 0 && tid < 16) {
            ushort4 z = {0, 0, 0, 0};
            ((ushort4*)(xb + (size_t)NN * FD))[tid] = z;
            ((ushort4*)(h1b + (size_t)NN * FD))[tid] = z;
        }
        if (bb == 0 && tid == 16) {
            ctrs[0] = 0;  // scanCol arrival counter
            ctrs[1] = 0;  // mlp1 arrival counter
        }
        int i = bb * 256 + tid;
        int st = 2048 * 256;
        for (; i < n4; i += st) {
            float4 v = x4[i];
            ushort4 w;
            w.x = f2bf(v.x);
            w.y = f2bf(v.y);
            w.z = f2bf(v.z);
            w.w = f2bf(v.w);
            xb4[i] = w;
        }
    }
}

// ---------------- CSR build: column scan + fused bucket-total scan ----------
// Each block scans one bucket's column of ghist; the LAST block to finish
// additionally performs the bucket-total exclusive scan (old k_scanB2) and
// zeroes the stats region S.
__global__ __launch_bounds__(512) void k_scanCol(int* __restrict__ ghist,
                                                 int* __restrict__ tot, int np1,
                                                 int* __restrict__ bbase,
                                                 float* __restrict__ S,
                                                 int* __restrict__ ctr) {
    __shared__ int ts[512];
    __shared__ int isLast;
    int b = blockIdx.x;
    int tid = threadIdx.x;
    int v = (tid < np1) ? ghist[(size_t)tid * NBP + b] : 0;
    ts[tid] = v;
    __syncthreads();
    for (int off = 1; off < 512; off <<= 1) {
        int u = (tid >= off) ? ts[tid - off] : 0;
        __syncthreads();
        ts[tid] += u;
        __syncthreads();
    }
    if (tid < np1) ghist[(size_t)tid * NBP + b] = ts[tid] - v;
    if (tid == 511) tot[b] = ts[511];
    __syncthreads();
    if (tid == 0) {
        __threadfence();
        isLast = (atomicAdd(ctr, 1) == NB - 1);
    }
    __syncthreads();
    if (!isLast) return;
    __threadfence();  // acquire: all blocks' tot[] writes visible
    if (tid < 192) S[tid] = 0.f;
    int v2 = (tid < NB) ? tot[tid] : 0;
    ts[tid] = v2;
    __syncthreads();
    for (int off = 1; off < 512; off <<= 1) {
        int u = (tid >= off) ? ts[tid - off] : 0;
        __syncthreads();
        ts[tid] += u;
        __syncthreads();
    }
    if (tid < NB) bbase[tid] = ts[tid] - v2;
    if (tid == 511) bbase[NB] = ts[511];  // = E
}

__global__ __launch_bounds__(256) void k_p1b2(const int* __restrict__ ei,
                                              const int* __restrict__ ghist,
                                              const int* __restrict__ bbase,
                                              int* __restrict__ part, int E_) {
    __shared__ int cur[NB];
    int tid = threadIdx.x;
    const int* row = ghist + (size_t)blockIdx.x * NBP;
    for (int i = tid; i < NB; i += 256) cur[i] = bbase[i] + row[i];
    __syncthreads();
    int c0 = blockIdx.x * P1CH;
    int c1 = min(c0 + P1CH, E_);
    for (int i = c0 + tid; i < c1; i += 256) {
        int s = ei[i];
        int d = ei[E_ + i];
        int b = min(max(d >> 8, 0), NB - 1);
        int slot = atomicAdd(&cur[b], 1);  // LDS returning atomic
        part[slot] = ((d & 255) << 20) | (s & 0xFFFFF);
    }
}

// per-bucket counting sort -> rowptr + csr. Single global pass: the bucket's
// edges are staged in LDS during counting (global re-read fallback if > BCAP).
__global__ __launch_bounds__(256) void k_build(const int* __restrict__ part,
                                               const int* __restrict__ bbase,
                                               int* __restrict__ rowptr,
                                               int* __restrict__ csr, int E_) {
    __shared__ int cnt[256];
    __shared__ int ts[256];
    __shared__ int cur[256];
    __shared__ int ebuf[BCAP];
    int b = blockIdx.x;
    int tid = threadIdx.x;
    cnt[tid] = 0;
    __syncthreads();
    int s0 = bbase[b], s1 = bbase[b + 1];
    int len = s1 - s0;
    bool inLds = (len <= BCAP);
    if (inLds) {
        for (int i = tid; i < len; i += 256) {
            int v = part[s0 + i];
            ebuf[i] = v;
            atomicAdd(&cnt[(v >> 20) & 255], 1);
        }
    } else {
        for (int i = tid; i < len; i += 256) {
            int v = part[s0 + i];
            atomicAdd(&cnt[(v >> 20) & 255], 1);
        }
    }
    __syncthreads();
    int v = cnt[tid];
    ts[tid] = v;
    __syncthreads();
    for (int off = 1; off < 256; off <<= 1) {
        int u = (tid >= off) ? ts[tid - off] : 0;
        __syncthreads();
        ts[tid] += u;
        __syncthreads();
    }
    int excl = ts[tid] - v;
    int node = b * 256 + tid;
    if (node < NN) rowptr[node] = s0 + excl;
    cur[tid] = s0 + excl;
    if (b == 0 && tid == 0) rowptr[NN] = E_;
    __syncthreads();
    if (inLds) {
        for (int i = tid; i < len; i += 256) {
            int v2 = ebuf[i];
            int lj = (v2 >> 20) & 255;
            int pos = atomicAdd(&cur[lj], 1);  // LDS returning atomic
            csr[pos] = v2 & 0xFFFFF;
        }
    } else {
        for (int i = tid; i < len; i += 256) {
            int v2 = part[s0 + i];
            int lj = (v2 >> 20) & 255;
            int pos = atomicAdd(&cur[lj], 1);
            csr[pos] = v2 & 0xFFFFF;
        }
    }
}

// ---------------- gather v2.2: 4 groups x 16 lanes, uint2 per lane ----------
// Zero-row sentinel for masked lanes; packed f32x2 accumulators.

#define GSTEP(T, A01, A23)                                                     \
    {                                                                          \
        int s = __shfl(id, (T) * 4 + g);                                       \
        uint2 v = *(const uint2*)(Xb + ((long)s << 6) + (l << 2));             \
        f32x2 p, q2;                                                           \
        p[0] = __uint_as_float(v.x << 16);                                     \
        p[1] = __uint_as_float(v.x & 0xFFFF0000u);                             \
        q2[0] = __uint_as_float(v.y << 16);                                    \
        q2[1] = __uint_as_float(v.y & 0xFFFF0000u);                            \
        A01 += p;                                                              \
        A23 += q2;                                                             \
    }

__global__ __launch_bounds__(256) void k_gather2(
        const ushort* __restrict__ Xb, const int* __restrict__ rowptr,
        const int* __restrict__ csr,
        const float* __restrict__ bs, const float* __restrict__ bq,
        const float* __restrict__ gam, const float* __restrict__ bet,
        ushort* __restrict__ outb, int affine) {
    int tid = threadIdx.x;
    int lane = tid & 63;
    int n = (blockIdx.x * blockDim.x + tid) >> 6;
    if (n >= NN) return;
    int g = lane >> 4;   // 0..3
    int l = lane & 15;   // features 4l..4l+3
    int start = rowptr[n], end = rowptr[n + 1];
    int deg = end - start;

    f32x2 a01 = {0.f, 0.f}, a23 = {0.f, 0.f};
    f32x2 b01 = {0.f, 0.f}, b23 = {0.f, 0.f};
    if (g == 0) {  // self row
        uint2 v = *(const uint2*)(Xb + ((long)n << 6) + (l << 2));
        a01[0] = __uint_as_float(v.x << 16);
        a01[1] = __uint_as_float(v.x & 0xFFFF0000u);
        a23[0] = __uint_as_float(v.y << 16);
        a23[1] = __uint_as_float(v.y & 0xFFFF0000u);
    }

    for (int base = start; base < end; base += 64) {
        int cnt = min(end - base, 64);
        int id = NN;  // zero-row sentinel for lanes >= cnt
        if (lane < cnt) id = csr[base + lane];
        int nsteps = (cnt + 3) >> 2;
        int t = 0;
        for (; t + 4 <= nsteps; t += 4) {
            GSTEP(t + 0, a01, a23)
            GSTEP(t + 1, b01, b23)
            GSTEP(t + 2, a01, a23)
            GSTEP(t + 3, b01, b23)
        }
        for (; t + 2 <= nsteps; t += 2) {
            GSTEP(t + 0, a01, a23)
            GSTEP(t + 1, b01, b23)
        }
        if (t < nsteps) GSTEP(t, a01, a23)
    }
    a01 += b01;
    a23 += b23;
    float A[4] = {a01[0], a01[1], a23[0], a23[1]};
#pragma unroll
    for (int c = 0; c < 4; c++) {
        float v = A[c];
        v += __shfl_xor(v, 16);
        v += __shfl_xor(v, 32);
        A[c] = v;
    }

    if (g == 0) {
        if (affine) {  // folded BN1 finalize + affine (16 writing lanes only)
            float dp1 = (float)(deg + 1);
#pragma unroll
            for (int c = 0; c < 4; c++) {
                int ch = l * 4 + c;
                float mu = bs[ch] * (1.f / NN);
                float var = bq[ch] * (1.f / NN) - mu * mu;
                float s = gam[ch] * rsqrtf(var + 1e-5f);
                float sh = fmaf(-mu, s, bet[ch]);
                A[c] = fmaf(A[c], s, dp1 * sh);
            }
        }
        ushort4 v;
        v.x = f2bf(A[0]); v.y = f2bf(A[1]); v.z = f2bf(A[2]); v.w = f2bf(A[3]);
        ((ushort4*)(outb + ((long)n << 6)))[l] = v;
    }
}

// ---------------- MFMA MLP kernels ----------------
// mlp1: per-block BN1 partials; LAST block reduces them into gsum1/gsq1.

__global__ __launch_bounds__(256) void k_mlp1_mfma(
        const ushort* __restrict__ Ab,
        const float* __restrict__ Wa, const float* __restrict__ ba,
        const float* __restrict__ Wb, const float* __restrict__ bb,
        ushort* __restrict__ H, float* __restrict__ gp1s, float* __restrict__ gp1q,
        float* __restrict__ gsum, float* __restrict__ gsq, int* __restrict__ ctr) {
    __shared__ __attribute__((aligned(16))) short tile[4][16 * 72];
    __shared__ float sArr[64], qArr[64];
    __shared__ float rs[256], rq[256];
    __shared__ int isLast;
    int tid = threadIdx.x;
    int w = tid >> 6, lane = tid & 63;
    int l = lane & 15, quad = lane >> 4;
    if (tid < 64) { sArr[tid] = 0.f; qArr[tid] = 0.f; }
    __syncthreads();

    bf16x8 B1[2][4], B2[2][4];
#pragma unroll
    for (int ks = 0; ks < 2; ks++)
#pragma unroll
        for (int t = 0; t < 4; t++) {
            bf16x8 f1, f2;
#pragma unroll
            for (int j = 0; j < 8; j++) {
                int k = ks * 32 + quad * 8 + j;
                f1[j] = (short)f2bf(Wa[k * 64 + t * 16 + l]);
                f2[j] = (short)f2bf(Wb[k * 64 + t * 16 + l]);
            }
            B1[ks][t] = f1;
            B2[ks][t] = f2;
        }
    float bias1[4], bias2[4];
#pragma unroll
    for (int t = 0; t < 4; t++) {
        bias1[t] = ba[t * 16 + l];
        bias2[t] = bb[t * 16 + l];
    }

    float s[4] = {0.f, 0.f, 0.f, 0.f}, q[4] = {0.f, 0.f, 0.f, 0.f};
    short* tp = &tile[w][0];
    int gw = blockIdx.x * 4 + w;
    int nw = gridDim.x * 4;
    bf16x8 A0, A1;
    if (gw < NTILE) {
        int m0 = gw * 16;
        A0 = *(const bf16x8*)(Ab + (size_t)(m0 + l) * FD + quad * 8);
        A1 = *(const bf16x8*)(Ab + (size_t)(m0 + l) * FD + 32 + quad * 8);
    }
    for (int tau = gw; tau < NTILE; tau += nw) {
        int m0 = tau * 16;
        int nxt = tau + nw;
        bf16x8 nA0, nA1;
        if (nxt < NTILE) {  // prefetch next tile's A while computing this one
            int nm0 = nxt * 16;
            nA0 = *(const bf16x8*)(Ab + (size_t)(nm0 + l) * FD + quad * 8);
            nA1 = *(const bf16x8*)(Ab + (size_t)(nm0 + l) * FD + 32 + quad * 8);
        }
#pragma unroll
        for (int t = 0; t < 4; t++) {
            f32x4 c = {0.f, 0.f, 0.f, 0.f};
            c = __builtin_amdgcn_mfma_f32_16x16x32_bf16(A0, B1[0][t], c, 0, 0, 0);
            c = __builtin_amdgcn_mfma_f32_16x16x32_bf16(A1, B1[1][t], c, 0, 0, 0);
#pragma unroll
            for (int r = 0; r < 4; r++) {
                float v = fmaxf(c[r] + bias1[t], 0.f);
                tp[(quad * 4 + r) * 72 + t * 16 + l] = (short)f2bf(v);
            }
        }
        bf16x8 A20 = *(const bf16x8*)&tp[l * 72 + quad * 8];
        bf16x8 A21 = *(const bf16x8*)&tp[l * 72 + 32 + quad * 8];
#pragma unroll
        for (int t = 0; t < 4; t++) {
            f32x4 c = {0.f, 0.f, 0.f, 0.f};
            c = __builtin_amdgcn_mfma_f32_16x16x32_bf16(A20, B2[0][t], c, 0, 0, 0);
            c = __builtin_amdgcn_mfma_f32_16x16x32_bf16(A21, B2[1][t], c, 0, 0, 0);
#pragma unroll
            for (int r = 0; r < 4; r++) {
                float v = fmaxf(c[r] + bias2[t], 0.f);
                s[t] += v;
                q[t] += v * v;
                tp[(quad * 4 + r) * 72 + t * 16 + l] = (short)f2bf(v);
            }
        }
        int row = lane >> 2, ch = lane & 3;
        bf16x8 o0 = *(const bf16x8*)&tp[row * 72 + ch * 16];
        bf16x8 o1 = *(const bf16x8*)&tp[row * 72 + ch * 16 + 8];
        *(bf16x8*)(H + (size_t)(m0 + row) * FD + ch * 16) = o0;
        *(bf16x8*)(H + (size_t)(m0 + row) * FD + ch * 16 + 8) = o1;
        A0 = nA0;
        A1 = nA1;
    }
#pragma unroll
    for (int t = 0; t < 4; t++) {
        s[t] += __shfl_xor(s[t], 16); s[t] += __shfl_xor(s[t], 32);
        q[t] += __shfl_xor(q[t], 16); q[t] += __shfl_xor(q[t], 32);
    }
    if (quad == 0) {
#pragma unroll
        for (int t = 0; t < 4; t++) {
            atomicAdd(&sArr[t * 16 + l], s[t]);
            atomicAdd(&qArr[t * 16 + l], q[t]);
        }
    }
    __syncthreads();
    if (tid < 64) {  // plain stores — no contended global atomics
        gp1s[tid * GPSTR + blockIdx.x] = sArr[tid];
        gp1q[tid * GPSTR + blockIdx.x] = qArr[tid];
    }
    __syncthreads();
    if (tid == 0) {
        __threadfence();
        isLast = (atomicAdd(ctr, 1) == (int)gridDim.x - 1);
    }
    __syncthreads();
    if (!isLast) return;
    __threadfence();  // acquire: all blocks' partials visible
    int ch = tid & 63, seg = tid >> 6;  // 4 segments per channel
    float ss = 0.f, qq = 0.f;
    for (int k = seg; k < MLPB; k += 4) {
        ss += gp1s[ch * GPSTR + k];
        qq += gp1q[ch * GPSTR + k];
    }
    rs[tid] = ss;
    rq[tid] = qq;
    __syncthreads();
    if (tid < 64) {
        gsum[ch] = rs[tid] + rs[tid + 64] + rs[tid + 128] + rs[tid + 192];
        gsq[ch] = rq[tid] + rq[tid + 64] + rq[tid + 128] + rq[tid + 192];
    }
}

__global__ __launch_bounds__(256) void k_mlp2_mfma(
        const ushort* __restrict__ Ab,
        const float* __restrict__ Wa, const float* __restrict__ ba,
        const float* __restrict__ Wb2, const float* __restrict__ bb2,
        float* __restrict__ O, float* __restrict__ gsum, float* __restrict__ gsq) {
    __shared__ __attribute__((aligned(16))) short tile[4][16 * 72];
    __shared__ float sArr[2], qArr[2];
    int tid = threadIdx.x;
    int w = tid >> 6, lane = tid & 63;
    int l = lane & 15, quad = lane >> 4;
    if (tid < 2) { sArr[tid] = 0.f; qArr[tid] = 0.f; }
    __syncthreads();

    bf16x8 B1[2][4], B2[2];
#pragma unroll
    for (int ks = 0; ks < 2; ks++) {
#pragma unroll
        for (int t = 0; t < 4; t++) {
            bf16x8 f1;
#pragma unroll
            for (int j = 0; j < 8; j++) {
                int k = ks * 32 + quad * 8 + j;
                f1[j] = (short)f2bf(Wa[k * 64 + t * 16 + l]);
            }
            B1[ks][t] = f1;
        }
        bf16x8 f2;
#pragma unroll
        for (int j = 0; j < 8; j++) {
            int k = ks * 32 + quad * 8 + j;
            f2[j] = (l < OUTF) ? (short)f2bf(Wb2[k * OUTF + l]) : (short)0;
        }
        B2[ks] = f2;
    }
    float bias1[4];
#pragma unroll
    for (int t = 0; t < 4; t++) bias1[t] = ba[t * 16 + l];
    float bias2 = (l < OUTF) ? bb2[l] : 0.f;

    float s = 0.f, q = 0.f;
    short* tp = &tile[w][0];
    int gw = blockIdx.x * 4 + w;
    int nw = gridDim.x * 4;
    bf16x8 A0, A1;
    if (gw < NTILE) {
        int m0 = gw * 16;
        A0 = *(const bf16x8*)(Ab + (size_t)(m0 + l) * FD + quad * 8);
        A1 = *(const bf16x8*)(Ab + (size_t)(m0 + l) * FD + 32 + quad * 8);
    }
    for (int tau = gw; tau < NTILE; tau += nw) {
        int m0 = tau * 16;
        int nxt = tau + nw;
        bf16x8 nA0, nA1;
        if (nxt < NTILE) {
            int nm0 = nxt * 16;
            nA0 = *(const bf16x8*)(Ab + (size_t)(nm0 + l) * FD + quad * 8);
            nA1 = *(const bf16x8*)(Ab + (size_t)(nm0 + l) * FD + 32 + quad * 8);
        }
#pragma unroll
        for (int t = 0; t < 4; t++) {
            f32x4 c = {0.f, 0.f, 0.f, 0.f};
            c = __builtin_amdgcn_mfma_f32_16x16x32_bf16(A0, B1[0][t], c, 0, 0, 0);
            c = __builtin_amdgcn_mfma_f32_16x16x32_bf16(A1, B1[1][t], c, 0, 0, 0);
#pragma unroll
            for (int r = 0; r < 4; r++) {
                float v = fmaxf(c[r] + bias1[t], 0.f);
                tp[(quad * 4 + r) * 72 + t * 16 + l] = (short)f2bf(v);
            }
        }
        bf16x8 A20 = *(const bf16x8*)&tp[l * 72 + quad * 8];
        bf16x8 A21 = *(const bf16x8*)&tp[l * 72 + 32 + quad * 8];
        f32x4 c = {0.f, 0.f, 0.f, 0.f};
        c = __builtin_amdgcn_mfma_f32_16x16x32_bf16(A20, B2[0], c, 0, 0, 0);
        c = __builtin_amdgcn_mfma_f32_16x16x32_bf16(A21, B2[1], c, 0, 0, 0);
#pragma unroll
        for (int r = 0; r < 4; r++) {
            float v = fmaxf(c[r] + bias2, 0.f);
            if (l < OUTF) {
                s += v;
                q += v * v;
                O[(size_t)(m0 + quad * 4 + r) * OUTF + l] = v;
            }
        }
        A0 = nA0;
        A1 = nA1;
    }
    s += __shfl_xor(s, 16); s += __shfl_xor(s, 32);
    q += __shfl_xor(q, 16); q += __shfl_xor(q, 32);
    if (quad == 0 && l < OUTF) {
        atomicAdd(&sArr[l], s);
        atomicAdd(&qArr[l], q);
    }
    __syncthreads();
    if (tid < OUTF) {  // only 2 atomics/block — negligible contention
        atomicAdd(&gsum[tid], sArr[tid]);
        atomicAdd(&gsq[tid], qArr[tid]);
    }
}

// ---------------- VALU MLP kernels (fallback path only) ----------------
template <bool BF16OUT>
__global__ __launch_bounds__(256) void k_mlp64(
        const float* __restrict__ X,
        const float* __restrict__ Wa, const float* __restrict__ ba,
        const float* __restrict__ Wb, const float* __restrict__ bb,
        void* __restrict__ Hv, float* __restrict__ gsum, float* __restrict__ gsq) {
    __shared__ float row[256 * 65];
    int tid = threadIdx.x;
    long node = (long)blockIdx.x * 256 + tid;
    bool valid = node < NN;
    if (valid) {
        const float4* rp = (const float4*)(X + node * FD);
#pragma unroll
        for (int q = 0; q < 16; q++) {
            float4 v = rp[q];
            row[tid * 65 + 4 * q + 0] = v.x;
            row[tid * 65 + 4 * q + 1] = v.y;
            row[tid * 65 + 4 * q + 2] = v.z;
            row[tid * 65 + 4 * q + 3] = v.w;
        }
    }
    float acc[64];
#pragma unroll
    for (int j = 0; j < 64; j++) acc[j] = ba[j];
    if (valid) {
        for (int k = 0; k < 64; k++) {
            float xv = row[tid * 65 + k];
            const float* wr = Wa + k * 64;
#pragma unroll
            for (int j = 0; j < 64; j++) acc[j] = fmaf(xv, wr[j], acc[j]);
        }
    }
#pragma unroll
    for (int j = 0; j < 64; j++) row[tid * 65 + j] = fmaxf(acc[j], 0.f);
#pragma unroll
    for (int j = 0; j < 64; j++) acc[j] = bb[j];
    if (valid) {
        for (int k = 0; k < 64; k++) {
            float xv = row[tid * 65 + k];
            const float* wr = Wb + k * 64;
#pragma unroll
            for (int j = 0; j < 64; j++) acc[j] = fmaf(xv, wr[j], acc[j]);
        }
    }
#pragma unroll
    for (int j = 0; j < 64; j++) {
        float v = valid ? fmaxf(acc[j], 0.f) : 0.f;
        row[tid * 65 + j] = v;
    }
    if (valid) {
        if (BF16OUT) {
            ushort4* op = (ushort4*)((ushort*)Hv + node * FD);
#pragma unroll
            for (int q = 0; q < 16; q++) {
                ushort4 w;
                w.x = f2bf(row[tid * 65 + 4 * q + 0]);
                w.y = f2bf(row[tid * 65 + 4 * q + 1]);
                w.z = f2bf(row[tid * 65 + 4 * q + 2]);
                w.w = f2bf(row[tid * 65 + 4 * q + 3]);
                op[q] = w;
            }
        } else {
            float4* op = (float4*)((float*)Hv + node * FD);
#pragma unroll
            for (int q = 0; q < 16; q++) {
                float4 v;
                v.x = row[tid * 65 + 4 * q + 0];
                v.y = row[tid * 65 + 4 * q + 1];
                v.z = row[tid * 65 + 4 * q + 2];
                v.w = row[tid * 65 + 4 * q + 3];
                op[q] = v;
            }
        }
    }
    __syncthreads();
    if (tid < 64) {
        float s = 0.f, q = 0.f;
        for (int r = 0; r < 256; r++) {
            float v = row[r * 65 + tid];
            s += v;
            q += v * v;
        }
        atomicAdd(&gsum[tid], s);
        atomicAdd(&gsq[tid], q);
    }
}

__global__ __launch_bounds__(256) void k_mlp_out(
        const float* __restrict__ X,
        const float* __restrict__ Wa, const float* __restrict__ ba,
        const float* __restrict__ Wb, const float* __restrict__ bb,
        float* __restrict__ O, float* __restrict__ gsum, float* __restrict__ gsq) {
    __shared__ float row[256 * 65];
    __shared__ float red[256][4];
    int tid = threadIdx.x;
    long node = (long)blockIdx.x * 256 + tid;
    bool valid = node < NN;
    if (valid) {
        const float4* rp = (const float4*)(X + node * FD);
#pragma unroll
        for (int q = 0; q < 16; q++) {
            float4 v = rp[q];
            row[tid * 65 + 4 * q + 0] = v.x;
            row[tid * 65 + 4 * q + 1] = v.y;
            row[tid * 65 + 4 * q + 2] = v.z;
            row[tid * 65 + 4 * q + 3] = v.w;
        }
    }
    float acc[64];
#pragma unroll
    for (int j = 0; j < 64; j++) acc[j] = ba[j];
    if (valid) {
        for (int k = 0; k < 64; k++) {
            float xv = row[tid * 65 + k];
            const float* wr = Wa + k * 64;
#pragma unroll
            for (int j = 0; j < 64; j++) acc[j] = fmaf(xv, wr[j], acc[j]);
        }
    }
#pragma unroll
    for (int j = 0; j < 64; j++) row[tid * 65 + j] = fmaxf(acc[j], 0.f);
    float a0 = bb[0];
    float a1 = bb[1];
    if (valid) {
        for (int k = 0; k < 64; k++) {
            float xv = row[tid * 65 + k];
            a0 = fmaf(xv, Wb[k * 2 + 0], a0);
            a1 = fmaf(xv, Wb[k * 2 + 1], a1);
        }
    }
    float v0 = valid ? fmaxf(a0, 0.f) : 0.f;
    float v1 = valid ? fmaxf(a1, 0.f) : 0.f;
    if (valid) {
        float2 v;
        v.x = v0;
        v.y = v1;
        ((float2*)O)[node] = v;
    }
    red[tid][0] = v0;
    red[tid][1] = v0 * v0;
    red[tid][2] = v1;
    red[tid][3] = v1 * v1;
    __syncthreads();
    for (int off = 128; off > 0; off >>= 1) {
        if (tid < off) {
#pragma unroll
            for (int c = 0; c < 4; c++) red[tid][c] += red[tid + off][c];
        }
        __syncthreads();
    }
    if (tid == 0) {
        atomicAdd(&gsum[0], red[0][0]);
        atomicAdd(&gsq[0], red[0][1]);
        atomicAdd(&gsum[1], red[0][2]);
        atomicAdd(&gsq[1], red[0][3]);
    }
}

// ---------------- batchnorm finalize / apply ----------------

__global__ void k_bnfin(const float* __restrict__ gsum, const float* __restrict__ gsq,
                        const float* __restrict__ g, const float* __restrict__ be,
                        float* __restrict__ sc, float* __restrict__ sh, int C, float invN) {
    int c = threadIdx.x;
    if (c < C) {
        float mu = gsum[c] * invN;
        float var = gsq[c] * invN - mu * mu;
        float s = g[c] * rsqrtf(var + 1e-5f);
        sc[c] = s;
        sh[c] = fmaf(-mu, s, be[c]);
    }
}

// merged finalize+apply for BN2 (2 channels): scale computed inline per thread
__global__ void k_bnfin_apply2(const float* __restrict__ gsum,
                               const float* __restrict__ gsq,
                               const float* __restrict__ g,
                               const float* __restrict__ be,
                               float* __restrict__ o, int n) {
    int i = blockIdx.x * blockDim.x + threadIdx.x;
    if (i < n) {
        int c = i & 1;
        float mu = gsum[c] * (1.f / NN);
        float var = gsq[c] * (1.f / NN) - mu * mu;
        float s = g[c] * rsqrtf(var + 1e-5f);
        float sh = fmaf(-mu, s, be[c]);
        o[i] = fmaf(o[i], s, sh);
    }
}

__global__ void k_bn_apply2(float* __restrict__ o, const float* __restrict__ sc,
                            const float* __restrict__ sh, int n) {
    int i = blockIdx.x * blockDim.x + threadIdx.x;
    if (i < n) {
        int c = i & 1;
        o[i] = fmaf(o[i], sc[c], sh[c]);
    }
}

// ---------------- fallback (round-1) atomic scatter kernels ----------------

__global__ void k_scatter(const float* __restrict__ x, const int* __restrict__ ei,
                          float* __restrict__ agg, int E_) {
    int lane = threadIdx.x & 63;
    int wid = (blockIdx.x * blockDim.x + threadIdx.x) >> 6;
    int nw = (gridDim.x * blockDim.x) >> 6;
    for (long e = wid; e < E_; e += nw) {
        int s = ei[e];
        int d = ei[E_ + e];
        float v = x[(long)s * FD + lane];
        atomicAdd(&agg[(long)d * FD + lane], v);
    }
}

__global__ void k_scatter_bn(const float* __restrict__ h, const int* __restrict__ ei,
                             const float* __restrict__ sc, const float* __restrict__ sh,
                             float* __restrict__ agg, int E_) {
    int lane = threadIdx.x & 63;
    float scl = sc[lane];
    float shf = sh[lane];
    int wid = (blockIdx.x * blockDim.x + threadIdx.x) >> 6;
    int nw = (gridDim.x * blockDim.x) >> 6;
    for (long e = wid; e < E_; e += nw) {
        int s = ei[e];
        int d = ei[E_ + e];
        float v = fmaf(h[(long)s * FD + lane], scl, shf);
        atomicAdd(&agg[(long)d * FD + lane], v);
    }
}

__global__ void k_bn_copy(const float4* __restrict__ h, const float4* __restrict__ sc4,
                          const float4* __restrict__ sh4, float4* __restrict__ o, int n4) {
    int i = blockIdx.x * blockDim.x + threadIdx.x;
    int st = gridDim.x * blockDim.x;
    for (; i < n4; i += st) {
        float4 v = h[i];
        int c = i & 15;
        float4 s = sc4[c];
        float4 b = sh4[c];
        v.x = fmaf(v.x, s.x, b.x);
        v.y = fmaf(v.y, s.y, b.y);
        v.z = fmaf(v.z, s.z, b.z);
        v.w = fmaf(v.w, s.w, b.w);
        o[i] = v;
    }
}

// ---------------- launch ----------------

extern "C" void kernel_launch(void* const* d_in, const int* in_sizes, int n_in,
                              void* d_out, int out_size, void* d_ws, size_t ws_size,
                              hipStream_t stream) {
    const float* x   = (const float*)d_in[0];
    const int*   ei  = (const int*)d_in[1];
    const float* W1a = (const float*)d_in[2];
    const float* b1a = (const float*)d_in[3];
    const float* W1b = (const float*)d_in[4];
    const float* b1b = (const float*)d_in[5];
    const float* g1  = (const float*)d_in[6];
    const float* be1 = (const float*)d_in[7];
    const float* W5a = (const float*)d_in[8];
    const float* b5a = (const float*)d_in[9];
    const float* W5b = (const float*)d_in[10];
    const float* b5b = (const float*)d_in[11];
    const float* g5  = (const float*)d_in[12];
    const float* be5 = (const float*)d_in[13];
    float* out = (float*)d_out;

    const int E = in_sizes[1] / 2;

    // Workspace layout (float units). Zero-row = 64 ushorts = 32 floats.
    float* ws = (float*)d_ws;
    float* agg = ws;                         // fallback f32 agg
    ushort* aggb = (ushort*)ws;              // [N*64] bf16 (fast path)
    float* gp1s = ws + 3200000;              // 64 x GPSTR BN1 partial sums
    float* gp1q = ws + 3260000;              // 64 x GPSTR BN1 partial sumsq
    ushort* xb  = (ushort*)(ws + 6400000);   // [(N+1)*64] bf16 (incl. zero row)
    ushort* h1b = (ushort*)(ws + 9600032);   // [(N+1)*64] bf16 (incl. zero row)
    float* h1_fb = ws + 6400000;             // fallback-only f32 h1 (overlaps xb/h1b)
    float* S   = ws + 12800064;              // 512 floats: stats & bn params
    float* gsum1  = S;        // 64
    float* gsq1   = S + 64;   // 64
    float* gsum2  = S + 128;  // 2
    float* gsq2   = S + 160;  // 2
    float* scale1 = S + 192;  // 64 (fallback)
    float* shift1 = S + 256;  // 64 (fallback)
    float* scale2 = S + 320;  // 2  (fallback)
    float* shift2 = S + 328;  // 2  (fallback)

    int* ibase  = (int*)(S + 512);
    int* rowptr = ibase;                  // NN+1 (padded to 100004)
    int* csr    = ibase + 100004;         // E
    int* bbase  = ibase + 100004 + E;     // NB+1 (pad 400)
    int* ctrs   = bbase + 396;            // 2 arrival counters (in bbase pad)
    int* tot    = bbase + 400;            // NB (pad 392)
    int* ghist  = tot + 392;              // np1 * NBP (np1 <= 512)
    int* part   = (int*)agg;              // E ints, aliased (used before aggb)

    const int np1 = (E + P1CH - 1) / P1CH;
    size_t needed = (size_t)(12800064 + 512) * 4 +
                    (size_t)(100004 + E + 400 + 392 + (size_t)np1 * NBP) * 4;

    const int n4 = NN * FD / 4;
    const int nblk = (NN + 255) / 256;  // 391

    if (ws_size >= needed && np1 <= 512) {
        // ---- 9-launch fast path ----
        k_cvt_hist<<<np1 + 2048, 256, 0, stream>>>(ei, ghist, E, np1, (const float4*)x,
                                                   (ushort4*)xb, xb, h1b, ctrs, n4);
        // column scans + (last block) bucket-total scan + S zeroing
        k_scanCol<<<NB, 512, 0, stream>>>(ghist, tot, np1, bbase, S, &ctrs[0]);
        k_p1b2<<<np1, 256, 0, stream>>>(ei, ghist, bbase, part, E);
        k_build<<<NB, 256, 0, stream>>>(part, bbase, rowptr, csr, E);

        // conv1: aggb = bf16(x + gather(x))
        k_gather2<<<25000, 256, 0, stream>>>(xb, rowptr, csr, nullptr, nullptr,
                                             nullptr, nullptr, aggb, 0);
        // conv1 MLP (MFMA) -> h1b; last block reduces BN1 partials
        k_mlp1_mfma<<<MLPB, 256, 0, stream>>>(aggb, W1a, b1a, W1b, b1b, h1b,
                                              gp1s, gp1q, gsum1, gsq1, &ctrs[1]);
        // conv5: aggb = bf16(bn(h1) + gather(bn(h1)))  [BN1 finalize folded in]
        k_gather2<<<25000, 256, 0, stream>>>(h1b, rowptr, csr, gsum1, gsq1,
                                             g1, be1, aggb, 1);
        // conv5 MLP (MFMA) -> out (+ BN2 stats)
        k_mlp2_mfma<<<MLPB, 256, 0, stream>>>(aggb, W5a, b5a, W5b, b5b, out, gsum2, gsq2);
        // BN2 finalize+apply fused
        k_bnfin_apply2<<<(NN * OUTF + 255) / 256, 256, 0, stream>>>(gsum2, gsq2, g5, be5,
                                                                    out, NN * OUTF);
    } else {
        // ---- fallback: round-1 atomic path (f32 throughout) ----
        k_zero<<<1, 256, 0, stream>>>(S, 192);
        k_copy4<<<4096, 256, 0, stream>>>((const float4*)x, (float4*)agg, n4);
        k_scatter<<<4096, 256, 0, stream>>>(x, ei, agg, E);
        k_mlp64<false><<<nblk, 256, 0, stream>>>(agg, W1a, b1a, W1b, b1b,
                                                 (void*)h1_fb, gsum1, gsq1);
        k_bnfin<<<1, 64, 0, stream>>>(gsum1, gsq1, g1, be1, scale1, shift1, 64, 1.f / NN);
        k_bn_copy<<<4096, 256, 0, stream>>>((const float4*)h1_fb, (const float4*)scale1,
                                            (const float4*)shift1, (float4*)agg, n4);
        k_scatter_bn<<<4096, 256, 0, stream>>>(h1_fb, ei, scale1, shift1, agg, E);
        k_mlp_out<<<nblk, 256, 0, stream>>>(agg, W5a, b5a, W5b, b5b, out, gsum2, gsq2);
        k_bnfin<<<1, 64, 0, stream>>>(gsum2, gsq2, g5, be5, scale2, shift2, OUTF, 1.f / NN);
        k_bn_apply2<<<(NN * OUTF + 255) / 256, 256, 0, stream>>>(out, scale2, shift2, NN * OUTF);
    }
}

// Round 15
// 254.253 us; speedup vs baseline: 1.4020x; 1.4020x over previous
//
#include <hip/hip_runtime.h>

#define NN 100000
#define FD 64
#define OUTF 2
#define NB 391        // ceil(NN/256) dst buckets, bucket = d >> 8
#define NBP 392       // padded ghist row stride
#define P1CH 4096     // edges per block in partition kernels
#define NTILE 6250    // NN/16 exactly
#define MLPB 782      // mlp grid blocks
#define GPSTR 800     // partial-array stride (>= MLPB)
#define BCAP 6016     // k_build LDS edge-buffer capacity (avg 4096/bucket)

typedef short bf16x8 __attribute__((ext_vector_type(8), may_alias));
typedef float f32x4 __attribute__((ext_vector_type(4)));
typedef float f32x2 __attribute__((ext_vector_type(2)));

// bf16 helpers (round-to-nearest-even)
__device__ inline ushort f2bf(float f) {
    uint u = __float_as_uint(f);
    uint r = (u + 0x7FFFu + ((u >> 16) & 1u)) >> 16;
    return (ushort)r;
}
__device__ inline float bf2f(ushort v) {
    return __uint_as_float(((uint)v) << 16);
}

// ---------------- utility kernels ----------------

__global__ void k_zero(float* __restrict__ p, int n) {
    int i = blockIdx.x * blockDim.x + threadIdx.x;
    if (i < n) p[i] = 0.f;
}

__global__ void k_copy4(const float4* __restrict__ s, float4* __restrict__ d, int n4) {
    int i = blockIdx.x * blockDim.x + threadIdx.x;
    int st = gridDim.x * blockDim.x;
    for (; i < n4; i += st) d[i] = s[i];
}

// standalone cvt (fallback path only)
__global__ void k_cvt(const float4* __restrict__ x4, ushort4* __restrict__ xb4, int n4) {
    int i = blockIdx.x * blockDim.x + threadIdx.x;
    int st = gridDim.x * blockDim.x;
    for (; i < n4; i += st) {
        float4 v = x4[i];
        ushort4 w;
        w.x = f2bf(v.x);
        w.y = f2bf(v.y);
        w.z = f2bf(v.z);
        w.w = f2bf(v.w);
        xb4[i] = w;
    }
}

// ---------------- fused cvt + bucket histogram (role-split grid) ----------
// NOTE (r14 post-mortem): no cross-block fences/last-block fusion anywhere —
// device-scope __threadfence on gfx950 = L2 writeback (per-XCD L2 non-
// coherent) and cost ~50 us in k_mlp1. Kernel boundaries are the cheap barrier.
__global__ __launch_bounds__(256) void k_cvt_hist(
        const int* __restrict__ ei, int* __restrict__ ghist, int E_, int np1,
        const float4* __restrict__ x4, ushort4* __restrict__ xb4,
        ushort* __restrict__ xb, ushort* __restrict__ h1b, int n4) {
    __shared__ int h[NB];
    int tid = threadIdx.x;
    int blk = blockIdx.x;
    if (blk < np1) {
        for (int i = tid; i < NB; i += 256) h[i] = 0;
        __syncthreads();
        int c0 = blk * P1CH;
        int c1 = min(c0 + P1CH, E_);
        for (int i = c0 + tid; i < c1; i += 256) {
            int d = ei[E_ + i];
            int b = min(max(d >> 8, 0), NB - 1);
            atomicAdd(&h[b], 1);
        }
        __syncthreads();
        int* row = ghist + (size_t)blk * NBP;
        for (int i = tid; i < NB; i += 256) row[i] = h[i];
    } else {
        int bb = blk - np1;
        if (bb == 0 && tid < 16) {
            ushort4 z = {0, 0, 0, 0};
            ((ushort4*)(xb + (size_t)NN * FD))[tid] = z;
            ((ushort4*)(h1b + (size_t)NN * FD))[tid] = z;
        }
        int i = bb * 256 + tid;
        int st = 2048 * 256;
        for (; i < n4; i += st) {
            float4 v = x4[i];
            ushort4 w;
            w.x = f2bf(v.x);
            w.y = f2bf(v.y);
            w.z = f2bf(v.z);
            w.w = f2bf(v.w);
            xb4[i] = w;
        }
    }
}

// ---------------- bucket-partitioned CSR build (v2: saved histograms) ----

__global__ __launch_bounds__(512) void k_scanCol(int* __restrict__ ghist,
                                                 int* __restrict__ tot, int np1) {
    __shared__ int ts[512];
    int b = blockIdx.x;
    int tid = threadIdx.x;
    int v = (tid < np1) ? ghist[(size_t)tid * NBP + b] : 0;
    ts[tid] = v;
    __syncthreads();
    for (int off = 1; off < 512; off <<= 1) {
        int u = (tid >= off) ? ts[tid - off] : 0;
        __syncthreads();
        ts[tid] += u;
        __syncthreads();
    }
    if (tid < np1) ghist[(size_t)tid * NBP + b] = ts[tid] - v;
    if (tid == 511) tot[b] = ts[511];
}

__global__ __launch_bounds__(512) void k_scanB2(const int* __restrict__ tot,
                                                int* __restrict__ bbase,
                                                float* __restrict__ S) {
    __shared__ int ts[512];
    int tid = threadIdx.x;
    if (tid < 192) S[tid] = 0.f;
    int v = (tid < NB) ? tot[tid] : 0;
    ts[tid] = v;
    __syncthreads();
    for (int off = 1; off < 512; off <<= 1) {
        int u = (tid >= off) ? ts[tid - off] : 0;
        __syncthreads();
        ts[tid] += u;
        __syncthreads();
    }
    if (tid < NB) bbase[tid] = ts[tid] - v;
    if (tid == 511) bbase[NB] = ts[511];  // = E
}

__global__ __launch_bounds__(256) void k_p1b2(const int* __restrict__ ei,
                                              const int* __restrict__ ghist,
                                              const int* __restrict__ bbase,
                                              int* __restrict__ part, int E_) {
    __shared__ int cur[NB];
    int tid = threadIdx.x;
    const int* row = ghist + (size_t)blockIdx.x * NBP;
    for (int i = tid; i < NB; i += 256) cur[i] = bbase[i] + row[i];
    __syncthreads();
    int c0 = blockIdx.x * P1CH;
    int c1 = min(c0 + P1CH, E_);
    for (int i = c0 + tid; i < c1; i += 256) {
        int s = ei[i];
        int d = ei[E_ + i];
        int b = min(max(d >> 8, 0), NB - 1);
        int slot = atomicAdd(&cur[b], 1);  // LDS returning atomic
        part[slot] = ((d & 255) << 20) | (s & 0xFFFFF);
    }
}

// per-bucket counting sort -> rowptr + csr. Single global pass: the bucket's
// edges are staged in LDS during counting (global re-read fallback if > BCAP).
__global__ __launch_bounds__(256) void k_build(const int* __restrict__ part,
                                               const int* __restrict__ bbase,
                                               int* __restrict__ rowptr,
                                               int* __restrict__ csr, int E_) {
    __shared__ int cnt[256];
    __shared__ int ts[256];
    __shared__ int cur[256];
    __shared__ int ebuf[BCAP];
    int b = blockIdx.x;
    int tid = threadIdx.x;
    cnt[tid] = 0;
    __syncthreads();
    int s0 = bbase[b], s1 = bbase[b + 1];
    int len = s1 - s0;
    bool inLds = (len <= BCAP);
    if (inLds) {
        for (int i = tid; i < len; i += 256) {
            int v = part[s0 + i];
            ebuf[i] = v;
            atomicAdd(&cnt[(v >> 20) & 255], 1);
        }
    } else {
        for (int i = tid; i < len; i += 256) {
            int v = part[s0 + i];
            atomicAdd(&cnt[(v >> 20) & 255], 1);
        }
    }
    __syncthreads();
    int v = cnt[tid];
    ts[tid] = v;
    __syncthreads();
    for (int off = 1; off < 256; off <<= 1) {
        int u = (tid >= off) ? ts[tid - off] : 0;
        __syncthreads();
        ts[tid] += u;
        __syncthreads();
    }
    int excl = ts[tid] - v;
    int node = b * 256 + tid;
    if (node < NN) rowptr[node] = s0 + excl;
    cur[tid] = s0 + excl;
    if (b == 0 && tid == 0) rowptr[NN] = E_;
    __syncthreads();
    if (inLds) {
        for (int i = tid; i < len; i += 256) {
            int v2 = ebuf[i];
            int lj = (v2 >> 20) & 255;
            int pos = atomicAdd(&cur[lj], 1);  // LDS returning atomic
            csr[pos] = v2 & 0xFFFFF;
        }
    } else {
        for (int i = tid; i < len; i += 256) {
            int v2 = part[s0 + i];
            int lj = (v2 >> 20) & 255;
            int pos = atomicAdd(&cur[lj], 1);
            csr[pos] = v2 & 0xFFFFF;
        }
    }
}

// ---------------- gather v2.2: 4 groups x 16 lanes, uint2 per lane ----------

#define GSTEP(T, A01, A23)                                                     \
    {                                                                          \
        int s = __shfl(id, (T) * 4 + g);                                       \
        uint2 v = *(const uint2*)(Xb + ((long)s << 6) + (l << 2));             \
        f32x2 p, q2;                                                           \
        p[0] = __uint_as_float(v.x << 16);                                     \
        p[1] = __uint_as_float(v.x & 0xFFFF0000u);                             \
        q2[0] = __uint_as_float(v.y << 16);                                    \
        q2[1] = __uint_as_float(v.y & 0xFFFF0000u);                            \
        A01 += p;                                                              \
        A23 += q2;                                                             \
    }

__global__ __launch_bounds__(256) void k_gather2(
        const ushort* __restrict__ Xb, const int* __restrict__ rowptr,
        const int* __restrict__ csr,
        const float* __restrict__ bs, const float* __restrict__ bq,
        const float* __restrict__ gam, const float* __restrict__ bet,
        ushort* __restrict__ outb, int affine) {
    int tid = threadIdx.x;
    int lane = tid & 63;
    int n = (blockIdx.x * blockDim.x + tid) >> 6;
    if (n >= NN) return;
    int g = lane >> 4;   // 0..3
    int l = lane & 15;   // features 4l..4l+3
    int start = rowptr[n], end = rowptr[n + 1];
    int deg = end - start;

    f32x2 a01 = {0.f, 0.f}, a23 = {0.f, 0.f};
    f32x2 b01 = {0.f, 0.f}, b23 = {0.f, 0.f};
    if (g == 0) {  // self row
        uint2 v = *(const uint2*)(Xb + ((long)n << 6) + (l << 2));
        a01[0] = __uint_as_float(v.x << 16);
        a01[1] = __uint_as_float(v.x & 0xFFFF0000u);
        a23[0] = __uint_as_float(v.y << 16);
        a23[1] = __uint_as_float(v.y & 0xFFFF0000u);
    }

    for (int base = start; base < end; base += 64) {
        int cnt = min(end - base, 64);
        int id = NN;  // zero-row sentinel for lanes >= cnt
        if (lane < cnt) id = csr[base + lane];
        int nsteps = (cnt + 3) >> 2;
        int t = 0;
        for (; t + 4 <= nsteps; t += 4) {
            GSTEP(t + 0, a01, a23)
            GSTEP(t + 1, b01, b23)
            GSTEP(t + 2, a01, a23)
            GSTEP(t + 3, b01, b23)
        }
        for (; t + 2 <= nsteps; t += 2) {
            GSTEP(t + 0, a01, a23)
            GSTEP(t + 1, b01, b23)
        }
        if (t < nsteps) GSTEP(t, a01, a23)
    }
    a01 += b01;
    a23 += b23;
    float A[4] = {a01[0], a01[1], a23[0], a23[1]};
#pragma unroll
    for (int c = 0; c < 4; c++) {
        float v = A[c];
        v += __shfl_xor(v, 16);
        v += __shfl_xor(v, 32);
        A[c] = v;
    }

    if (g == 0) {
        if (affine) {  // folded BN1 finalize + affine (16 writing lanes only)
            float dp1 = (float)(deg + 1);
#pragma unroll
            for (int c = 0; c < 4; c++) {
                int ch = l * 4 + c;
                float mu = bs[ch] * (1.f / NN);
                float var = bq[ch] * (1.f / NN) - mu * mu;
                float s = gam[ch] * rsqrtf(var + 1e-5f);
                float sh = fmaf(-mu, s, bet[ch]);
                A[c] = fmaf(A[c], s, dp1 * sh);
            }
        }
        ushort4 v;
        v.x = f2bf(A[0]); v.y = f2bf(A[1]); v.z = f2bf(A[2]); v.w = f2bf(A[3]);
        ((ushort4*)(outb + ((long)n << 6)))[l] = v;
    }
}

// ---------------- MFMA MLP kernels ----------------
// mlp1 stats: per-block partials (channel-major, no global atomics) + k_red1.

__global__ __launch_bounds__(256) void k_mlp1_mfma(
        const ushort* __restrict__ Ab,
        const float* __restrict__ Wa, const float* __restrict__ ba,
        const float* __restrict__ Wb, const float* __restrict__ bb,
        ushort* __restrict__ H, float* __restrict__ gp1s, float* __restrict__ gp1q) {
    __shared__ __attribute__((aligned(16))) short tile[4][16 * 72];
    __shared__ float sArr[64], qArr[64];
    int tid = threadIdx.x;
    int w = tid >> 6, lane = tid & 63;
    int l = lane & 15, quad = lane >> 4;
    if (tid < 64) { sArr[tid] = 0.f; qArr[tid] = 0.f; }
    __syncthreads();

    bf16x8 B1[2][4], B2[2][4];
#pragma unroll
    for (int ks = 0; ks < 2; ks++)
#pragma unroll
        for (int t = 0; t < 4; t++) {
            bf16x8 f1, f2;
#pragma unroll
            for (int j = 0; j < 8; j++) {
                int k = ks * 32 + quad * 8 + j;
                f1[j] = (short)f2bf(Wa[k * 64 + t * 16 + l]);
                f2[j] = (short)f2bf(Wb[k * 64 + t * 16 + l]);
            }
            B1[ks][t] = f1;
            B2[ks][t] = f2;
        }
    float bias1[4], bias2[4];
#pragma unroll
    for (int t = 0; t < 4; t++) {
        bias1[t] = ba[t * 16 + l];
        bias2[t] = bb[t * 16 + l];
    }

    float s[4] = {0.f, 0.f, 0.f, 0.f}, q[4] = {0.f, 0.f, 0.f, 0.f};
    short* tp = &tile[w][0];
    int gw = blockIdx.x * 4 + w;
    int nw = gridDim.x * 4;
    bf16x8 A0, A1;
    if (gw < NTILE) {
        int m0 = gw * 16;
        A0 = *(const bf16x8*)(Ab + (size_t)(m0 + l) * FD + quad * 8);
        A1 = *(const bf16x8*)(Ab + (size_t)(m0 + l) * FD + 32 + quad * 8);
    }
    for (int tau = gw; tau < NTILE; tau += nw) {
        int m0 = tau * 16;
        int nxt = tau + nw;
        bf16x8 nA0, nA1;
        if (nxt < NTILE) {  // prefetch next tile's A while computing this one
            int nm0 = nxt * 16;
            nA0 = *(const bf16x8*)(Ab + (size_t)(nm0 + l) * FD + quad * 8);
            nA1 = *(const bf16x8*)(Ab + (size_t)(nm0 + l) * FD + 32 + quad * 8);
        }
#pragma unroll
        for (int t = 0; t < 4; t++) {
            f32x4 c = {0.f, 0.f, 0.f, 0.f};
            c = __builtin_amdgcn_mfma_f32_16x16x32_bf16(A0, B1[0][t], c, 0, 0, 0);
            c = __builtin_amdgcn_mfma_f32_16x16x32_bf16(A1, B1[1][t], c, 0, 0, 0);
#pragma unroll
            for (int r = 0; r < 4; r++) {
                float v = fmaxf(c[r] + bias1[t], 0.f);
                tp[(quad * 4 + r) * 72 + t * 16 + l] = (short)f2bf(v);
            }
        }
        bf16x8 A20 = *(const bf16x8*)&tp[l * 72 + quad * 8];
        bf16x8 A21 = *(const bf16x8*)&tp[l * 72 + 32 + quad * 8];
#pragma unroll
        for (int t = 0; t < 4; t++) {
            f32x4 c = {0.f, 0.f, 0.f, 0.f};
            c = __builtin_amdgcn_mfma_f32_16x16x32_bf16(A20, B2[0][t], c, 0, 0, 0);
            c = __builtin_amdgcn_mfma_f32_16x16x32_bf16(A21, B2[1][t], c, 0, 0, 0);
#pragma unroll
            for (int r = 0; r < 4; r++) {
                float v = fmaxf(c[r] + bias2[t], 0.f);
                s[t] += v;
                q[t] += v * v;
                tp[(quad * 4 + r) * 72 + t * 16 + l] = (short)f2bf(v);
            }
        }
        int row = lane >> 2, ch = lane & 3;
        bf16x8 o0 = *(const bf16x8*)&tp[row * 72 + ch * 16];
        bf16x8 o1 = *(const bf16x8*)&tp[row * 72 + ch * 16 + 8];
        *(bf16x8*)(H + (size_t)(m0 + row) * FD + ch * 16) = o0;
        *(bf16x8*)(H + (size_t)(m0 + row) * FD + ch * 16 + 8) = o1;
        A0 = nA0;
        A1 = nA1;
    }
#pragma unroll
    for (int t = 0; t < 4; t++) {
        s[t] += __shfl_xor(s[t], 16); s[t] += __shfl_xor(s[t], 32);
        q[t] += __shfl_xor(q[t], 16); q[t] += __shfl_xor(q[t], 32);
    }
    if (quad == 0) {
#pragma unroll
        for (int t = 0; t < 4; t++) {
            atomicAdd(&sArr[t * 16 + l], s[t]);
            atomicAdd(&qArr[t * 16 + l], q[t]);
        }
    }
    __syncthreads();
    if (tid < 64) {  // plain stores — no contended global atomics
        gp1s[tid * GPSTR + blockIdx.x] = sArr[tid];
        gp1q[tid * GPSTR + blockIdx.x] = qArr[tid];
    }
}

// reduce per-block BN1 partials -> gsum1/gsq1 (64 blocks, one per channel)
__global__ __launch_bounds__(256) void k_red1(const float* __restrict__ gp1s,
                                              const float* __restrict__ gp1q,
                                              float* __restrict__ gsum,
                                              float* __restrict__ gsq, int nb) {
    __shared__ float rs[256], rq[256];
    int ch = blockIdx.x;
    int tid = threadIdx.x;
    float s = 0.f, q = 0.f;
    for (int k = tid; k < nb; k += 256) {
        s += gp1s[ch * GPSTR + k];
        q += gp1q[ch * GPSTR + k];
    }
    rs[tid] = s;
    rq[tid] = q;
    __syncthreads();
    for (int off = 128; off > 0; off >>= 1) {
        if (tid < off) {
            rs[tid] += rs[tid + off];
            rq[tid] += rq[tid + off];
        }
        __syncthreads();
    }
    if (tid == 0) {
        gsum[ch] = rs[0];
        gsq[ch] = rq[0];
    }
}

__global__ __launch_bounds__(256) void k_mlp2_mfma(
        const ushort* __restrict__ Ab,
        const float* __restrict__ Wa, const float* __restrict__ ba,
        const float* __restrict__ Wb2, const float* __restrict__ bb2,
        float* __restrict__ O, float* __restrict__ gsum, float* __restrict__ gsq) {
    __shared__ __attribute__((aligned(16))) short tile[4][16 * 72];
    __shared__ float sArr[2], qArr[2];
    int tid = threadIdx.x;
    int w = tid >> 6, lane = tid & 63;
    int l = lane & 15, quad = lane >> 4;
    if (tid < 2) { sArr[tid] = 0.f; qArr[tid] = 0.f; }
    __syncthreads();

    bf16x8 B1[2][4], B2[2];
#pragma unroll
    for (int ks = 0; ks < 2; ks++) {
#pragma unroll
        for (int t = 0; t < 4; t++) {
            bf16x8 f1;
#pragma unroll
            for (int j = 0; j < 8; j++) {
                int k = ks * 32 + quad * 8 + j;
                f1[j] = (short)f2bf(Wa[k * 64 + t * 16 + l]);
            }
            B1[ks][t] = f1;
        }
        bf16x8 f2;
#pragma unroll
        for (int j = 0; j < 8; j++) {
            int k = ks * 32 + quad * 8 + j;
            f2[j] = (l < OUTF) ? (short)f2bf(Wb2[k * OUTF + l]) : (short)0;
        }
        B2[ks] = f2;
    }
    float bias1[4];
#pragma unroll
    for (int t = 0; t < 4; t++) bias1[t] = ba[t * 16 + l];
    float bias2 = (l < OUTF) ? bb2[l] : 0.f;

    float s = 0.f, q = 0.f;
    short* tp = &tile[w][0];
    int gw = blockIdx.x * 4 + w;
    int nw = gridDim.x * 4;
    bf16x8 A0, A1;
    if (gw < NTILE) {
        int m0 = gw * 16;
        A0 = *(const bf16x8*)(Ab + (size_t)(m0 + l) * FD + quad * 8);
        A1 = *(const bf16x8*)(Ab + (size_t)(m0 + l) * FD + 32 + quad * 8);
    }
    for (int tau = gw; tau < NTILE; tau += nw) {
        int m0 = tau * 16;
        int nxt = tau + nw;
        bf16x8 nA0, nA1;
        if (nxt < NTILE) {
            int nm0 = nxt * 16;
            nA0 = *(const bf16x8*)(Ab + (size_t)(nm0 + l) * FD + quad * 8);
            nA1 = *(const bf16x8*)(Ab + (size_t)(nm0 + l) * FD + 32 + quad * 8);
        }
#pragma unroll
        for (int t = 0; t < 4; t++) {
            f32x4 c = {0.f, 0.f, 0.f, 0.f};
            c = __builtin_amdgcn_mfma_f32_16x16x32_bf16(A0, B1[0][t], c, 0, 0, 0);
            c = __builtin_amdgcn_mfma_f32_16x16x32_bf16(A1, B1[1][t], c, 0, 0, 0);
#pragma unroll
            for (int r = 0; r < 4; r++) {
                float v = fmaxf(c[r] + bias1[t], 0.f);
                tp[(quad * 4 + r) * 72 + t * 16 + l] = (short)f2bf(v);
            }
        }
        bf16x8 A20 = *(const bf16x8*)&tp[l * 72 + quad * 8];
        bf16x8 A21 = *(const bf16x8*)&tp[l * 72 + 32 + quad * 8];
        f32x4 c = {0.f, 0.f, 0.f, 0.f};
        c = __builtin_amdgcn_mfma_f32_16x16x32_bf16(A20, B2[0], c, 0, 0, 0);
        c = __builtin_amdgcn_mfma_f32_16x16x32_bf16(A21, B2[1], c, 0, 0, 0);
#pragma unroll
        for (int r = 0; r < 4; r++) {
            float v = fmaxf(c[r] + bias2, 0.f);
            if (l < OUTF) {
                s += v;
                q += v * v;
                O[(size_t)(m0 + quad * 4 + r) * OUTF + l] = v;
            }
        }
        A0 = nA0;
        A1 = nA1;
    }
    s += __shfl_xor(s, 16); s += __shfl_xor(s, 32);
    q += __shfl_xor(q, 16); q += __shfl_xor(q, 32);
    if (quad == 0 && l < OUTF) {
        atomicAdd(&sArr[l], s);
        atomicAdd(&qArr[l], q);
    }
    __syncthreads();
    if (tid < OUTF) {  // only 2 atomics/block — negligible contention
        atomicAdd(&gsum[tid], sArr[tid]);
        atomicAdd(&gsq[tid], qArr[tid]);
    }
}

// ---------------- VALU MLP kernels (fallback path only) ----------------
template <bool BF16OUT>
__global__ __launch_bounds__(256) void k_mlp64(
        const float* __restrict__ X,
        const float* __restrict__ Wa, const float* __restrict__ ba,
        const float* __restrict__ Wb, const float* __restrict__ bb,
        void* __restrict__ Hv, float* __restrict__ gsum, float* __restrict__ gsq) {
    __shared__ float row[256 * 65];
    int tid = threadIdx.x;
    long node = (long)blockIdx.x * 256 + tid;
    bool valid = node < NN;
    if (valid) {
        const float4* rp = (const float4*)(X + node * FD);
#pragma unroll
        for (int q = 0; q < 16; q++) {
            float4 v = rp[q];
            row[tid * 65 + 4 * q + 0] = v.x;
            row[tid * 65 + 4 * q + 1] = v.y;
            row[tid * 65 + 4 * q + 2] = v.z;
            row[tid * 65 + 4 * q + 3] = v.w;
        }
    }
    float acc[64];
#pragma unroll
    for (int j = 0; j < 64; j++) acc[j] = ba[j];
    if (valid) {
        for (int k = 0; k < 64; k++) {
            float xv = row[tid * 65 + k];
            const float* wr = Wa + k * 64;
#pragma unroll
            for (int j = 0; j < 64; j++) acc[j] = fmaf(xv, wr[j], acc[j]);
        }
    }
#pragma unroll
    for (int j = 0; j < 64; j++) row[tid * 65 + j] = fmaxf(acc[j], 0.f);
#pragma unroll
    for (int j = 0; j < 64; j++) acc[j] = bb[j];
    if (valid) {
        for (int k = 0; k < 64; k++) {
            float xv = row[tid * 65 + k];
            const float* wr = Wb + k * 64;
#pragma unroll
            for (int j = 0; j < 64; j++) acc[j] = fmaf(xv, wr[j], acc[j]);
        }
    }
#pragma unroll
    for (int j = 0; j < 64; j++) {
        float v = valid ? fmaxf(acc[j], 0.f) : 0.f;
        row[tid * 65 + j] = v;
    }
    if (valid) {
        if (BF16OUT) {
            ushort4* op = (ushort4*)((ushort*)Hv + node * FD);
#pragma unroll
            for (int q = 0; q < 16; q++) {
                ushort4 w;
                w.x = f2bf(row[tid * 65 + 4 * q + 0]);
                w.y = f2bf(row[tid * 65 + 4 * q + 1]);
                w.z = f2bf(row[tid * 65 + 4 * q + 2]);
                w.w = f2bf(row[tid * 65 + 4 * q + 3]);
                op[q] = w;
            }
        } else {
            float4* op = (float4*)((float*)Hv + node * FD);
#pragma unroll
            for (int q = 0; q < 16; q++) {
                float4 v;
                v.x = row[tid * 65 + 4 * q + 0];
                v.y = row[tid * 65 + 4 * q + 1];
                v.z = row[tid * 65 + 4 * q + 2];
                v.w = row[tid * 65 + 4 * q + 3];
                op[q] = v;
            }
        }
    }
    __syncthreads();
    if (tid < 64) {
        float s = 0.f, q = 0.f;
        for (int r = 0; r < 256; r++) {
            float v = row[r * 65 + tid];
            s += v;
            q += v * v;
        }
        atomicAdd(&gsum[tid], s);
        atomicAdd(&gsq[tid], q);
    }
}

__global__ __launch_bounds__(256) void k_mlp_out(
        const float* __restrict__ X,
        const float* __restrict__ Wa, const float* __restrict__ ba,
        const float* __restrict__ Wb, const float* __restrict__ bb,
        float* __restrict__ O, float* __restrict__ gsum, float* __restrict__ gsq) {
    __shared__ float row[256 * 65];
    __shared__ float red[256][4];
    int tid = threadIdx.x;
    long node = (long)blockIdx.x * 256 + tid;
    bool valid = node < NN;
    if (valid) {
        const float4* rp = (const float4*)(X + node * FD);
#pragma unroll
        for (int q = 0; q < 16; q++) {
            float4 v = rp[q];
            row[tid * 65 + 4 * q + 0] = v.x;
            row[tid * 65 + 4 * q + 1] = v.y;
            row[tid * 65 + 4 * q + 2] = v.z;
            row[tid * 65 + 4 * q + 3] = v.w;
        }
    }
    float acc[64];
#pragma unroll
    for (int j = 0; j < 64; j++) acc[j] = ba[j];
    if (valid) {
        for (int k = 0; k < 64; k++) {
            float xv = row[tid * 65 + k];
            const float* wr = Wa + k * 64;
#pragma unroll
            for (int j = 0; j < 64; j++) acc[j] = fmaf(xv, wr[j], acc[j]);
        }
    }
#pragma unroll
    for (int j = 0; j < 64; j++) row[tid * 65 + j] = fmaxf(acc[j], 0.f);
    float a0 = bb[0];
    float a1 = bb[1];
    if (valid) {
        for (int k = 0; k < 64; k++) {
            float xv = row[tid * 65 + k];
            a0 = fmaf(xv, Wb[k * 2 + 0], a0);
            a1 = fmaf(xv, Wb[k * 2 + 1], a1);
        }
    }
    float v0 = valid ? fmaxf(a0, 0.f) : 0.f;
    float v1 = valid ? fmaxf(a1, 0.f) : 0.f;
    if (valid) {
        float2 v;
        v.x = v0;
        v.y = v1;
        ((float2*)O)[node] = v;
    }
    red[tid][0] = v0;
    red[tid][1] = v0 * v0;
    red[tid][2] = v1;
    red[tid][3] = v1 * v1;
    __syncthreads();
    for (int off = 128; off > 0; off >>= 1) {
        if (tid < off) {
#pragma unroll
            for (int c = 0; c < 4; c++) red[tid][c] += red[tid + off][c];
        }
        __syncthreads();
    }
    if (tid == 0) {
        atomicAdd(&gsum[0], red[0][0]);
        atomicAdd(&gsq[0], red[0][1]);
        atomicAdd(&gsum[1], red[0][2]);
        atomicAdd(&gsq[1], red[0][3]);
    }
}

// ---------------- batchnorm finalize / apply ----------------

__global__ void k_bnfin(const float* __restrict__ gsum, const float* __restrict__ gsq,
                        const float* __restrict__ g, const float* __restrict__ be,
                        float* __restrict__ sc, float* __restrict__ sh, int C, float invN) {
    int c = threadIdx.x;
    if (c < C) {
        float mu = gsum[c] * invN;
        float var = gsq[c] * invN - mu * mu;
        float s = g[c] * rsqrtf(var + 1e-5f);
        sc[c] = s;
        sh[c] = fmaf(-mu, s, be[c]);
    }
}

// merged finalize+apply for BN2 (2 channels): scale computed inline per thread
__global__ void k_bnfin_apply2(const float* __restrict__ gsum,
                               const float* __restrict__ gsq,
                               const float* __restrict__ g,
                               const float* __restrict__ be,
                               float* __restrict__ o, int n) {
    int i = blockIdx.x * blockDim.x + threadIdx.x;
    if (i < n) {
        int c = i & 1;
        float mu = gsum[c] * (1.f / NN);
        float var = gsq[c] * (1.f / NN) - mu * mu;
        float s = g[c] * rsqrtf(var + 1e-5f);
        float sh = fmaf(-mu, s, be[c]);
        o[i] = fmaf(o[i], s, sh);
    }
}

__global__ void k_bn_apply2(float* __restrict__ o, const float* __restrict__ sc,
                            const float* __restrict__ sh, int n) {
    int i = blockIdx.x * blockDim.x + threadIdx.x;
    if (i < n) {
        int c = i & 1;
        o[i] = fmaf(o[i], sc[c], sh[c]);
    }
}

// ---------------- fallback (round-1) atomic scatter kernels ----------------

__global__ void k_scatter(const float* __restrict__ x, const int* __restrict__ ei,
                          float* __restrict__ agg, int E_) {
    int lane = threadIdx.x & 63;
    int wid = (blockIdx.x * blockDim.x + threadIdx.x) >> 6;
    int nw = (gridDim.x * blockDim.x) >> 6;
    for (long e = wid; e < E_; e += nw) {
        int s = ei[e];
        int d = ei[E_ + e];
        float v = x[(long)s * FD + lane];
        atomicAdd(&agg[(long)d * FD + lane], v);
    }
}

__global__ void k_scatter_bn(const float* __restrict__ h, const int* __restrict__ ei,
                             const float* __restrict__ sc, const float* __restrict__ sh,
                             float* __restrict__ agg, int E_) {
    int lane = threadIdx.x & 63;
    float scl = sc[lane];
    float shf = sh[lane];
    int wid = (blockIdx.x * blockDim.x + threadIdx.x) >> 6;
    int nw = (gridDim.x * blockDim.x) >> 6;
    for (long e = wid; e < E_; e += nw) {
        int s = ei[e];
        int d = ei[E_ + e];
        float v = fmaf(h[(long)s * FD + lane], scl, shf);
        atomicAdd(&agg[(long)d * FD + lane], v);
    }
}

__global__ void k_bn_copy(const float4* __restrict__ h, const float4* __restrict__ sc4,
                          const float4* __restrict__ sh4, float4* __restrict__ o, int n4) {
    int i = blockIdx.x * blockDim.x + threadIdx.x;
    int st = gridDim.x * blockDim.x;
    for (; i < n4; i += st) {
        float4 v = h[i];
        int c = i & 15;
        float4 s = sc4[c];
        float4 b = sh4[c];
        v.x = fmaf(v.x, s.x, b.x);
        v.y = fmaf(v.y, s.y, b.y);
        v.z = fmaf(v.z, s.z, b.z);
        v.w = fmaf(v.w, s.w, b.w);
        o[i] = v;
    }
}

// ---------------- launch ----------------

extern "C" void kernel_launch(void* const* d_in, const int* in_sizes, int n_in,
                              void* d_out, int out_size, void* d_ws, size_t ws_size,
                              hipStream_t stream) {
    const float* x   = (const float*)d_in[0];
    const int*   ei  = (const int*)d_in[1];
    const float* W1a = (const float*)d_in[2];
    const float* b1a = (const float*)d_in[3];
    const float* W1b = (const float*)d_in[4];
    const float* b1b = (const float*)d_in[5];
    const float* g1  = (const float*)d_in[6];
    const float* be1 = (const float*)d_in[7];
    const float* W5a = (const float*)d_in[8];
    const float* b5a = (const float*)d_in[9];
    const float* W5b = (const float*)d_in[10];
    const float* b5b = (const float*)d_in[11];
    const float* g5  = (const float*)d_in[12];
    const float* be5 = (const float*)d_in[13];
    float* out = (float*)d_out;

    const int E = in_sizes[1] / 2;

    // Workspace layout (float units). Zero-row = 64 ushorts = 32 floats.
    float* ws = (float*)d_ws;
    float* agg = ws;                         // fallback f32 agg
    ushort* aggb = (ushort*)ws;              // [N*64] bf16 (fast path)
    float* gp1s = ws + 3200000;              // 64 x GPSTR BN1 partial sums
    float* gp1q = ws + 3260000;              // 64 x GPSTR BN1 partial sumsq
    ushort* xb  = (ushort*)(ws + 6400000);   // [(N+1)*64] bf16 (incl. zero row)
    ushort* h1b = (ushort*)(ws + 9600032);   // [(N+1)*64] bf16 (incl. zero row)
    float* h1_fb = ws + 6400000;             // fallback-only f32 h1 (overlaps xb/h1b)
    float* S   = ws + 12800064;              // 512 floats: stats & bn params
    float* gsum1  = S;        // 64
    float* gsq1   = S + 64;   // 64
    float* gsum2  = S + 128;  // 2
    float* gsq2   = S + 160;  // 2
    float* scale1 = S + 192;  // 64 (fallback)
    float* shift1 = S + 256;  // 64 (fallback)
    float* scale2 = S + 320;  // 2  (fallback)
    float* shift2 = S + 328;  // 2  (fallback)

    int* ibase  = (int*)(S + 512);
    int* rowptr = ibase;                  // NN+1 (padded to 100004)
    int* csr    = ibase + 100004;         // E
    int* bbase  = ibase + 100004 + E;     // NB+1 (pad 400)
    int* tot    = bbase + 400;            // NB (pad 392)
    int* ghist  = tot + 392;              // np1 * NBP (np1 <= 512)
    int* part   = (int*)agg;              // E ints, aliased (used before aggb)

    const int np1 = (E + P1CH - 1) / P1CH;
    size_t needed = (size_t)(12800064 + 512) * 4 +
                    (size_t)(100004 + E + 400 + 392 + (size_t)np1 * NBP) * 4;

    const int n4 = NN * FD / 4;
    const int nblk = (NN + 255) / 256;  // 391

    if (ws_size >= needed && np1 <= 512) {
        // ---- r13 structure (no cross-block fences) + single-pass k_build ----
        k_cvt_hist<<<np1 + 2048, 256, 0, stream>>>(ei, ghist, E, np1, (const float4*)x,
                                                   (ushort4*)xb, xb, h1b, n4);
        k_scanCol<<<NB, 512, 0, stream>>>(ghist, tot, np1);
        k_scanB2<<<1, 512, 0, stream>>>(tot, bbase, S);  // also zeroes stats
        k_p1b2<<<np1, 256, 0, stream>>>(ei, ghist, bbase, part, E);
        k_build<<<NB, 256, 0, stream>>>(part, bbase, rowptr, csr, E);

        // conv1: aggb = bf16(x + gather(x))
        k_gather2<<<25000, 256, 0, stream>>>(xb, rowptr, csr, nullptr, nullptr,
                                             nullptr, nullptr, aggb, 0);
        // conv1 MLP (MFMA) -> h1b (+ BN1 partial stats)
        k_mlp1_mfma<<<MLPB, 256, 0, stream>>>(aggb, W1a, b1a, W1b, b1b, h1b, gp1s, gp1q);
        // reduce BN1 partials -> gsum1/gsq1
        k_red1<<<64, 256, 0, stream>>>(gp1s, gp1q, gsum1, gsq1, MLPB);
        // conv5: aggb = bf16(bn(h1) + gather(bn(h1)))  [BN1 finalize folded in]
        k_gather2<<<25000, 256, 0, stream>>>(h1b, rowptr, csr, gsum1, gsq1,
                                             g1, be1, aggb, 1);
        // conv5 MLP (MFMA) -> out (+ BN2 stats)
        k_mlp2_mfma<<<MLPB, 256, 0, stream>>>(aggb, W5a, b5a, W5b, b5b, out, gsum2, gsq2);
        // BN2 finalize+apply fused
        k_bnfin_apply2<<<(NN * OUTF + 255) / 256, 256, 0, stream>>>(gsum2, gsq2, g5, be5,
                                                                    out, NN * OUTF);
    } else {
        // ---- fallback: round-1 atomic path (f32 throughout) ----
        k_zero<<<1, 256, 0, stream>>>(S, 192);
        k_copy4<<<4096, 256, 0, stream>>>((const float4*)x, (float4*)agg, n4);
        k_scatter<<<4096, 256, 0, stream>>>(x, ei, agg, E);
        k_mlp64<false><<<nblk, 256, 0, stream>>>(agg, W1a, b1a, W1b, b1b,
                                                 (void*)h1_fb, gsum1, gsq1);
        k_bnfin<<<1, 64, 0, stream>>>(gsum1, gsq1, g1, be1, scale1, shift1, 64, 1.f / NN);
        k_bn_copy<<<4096, 256, 0, stream>>>((const float4*)h1_fb, (const float4*)scale1,
                                            (const float4*)shift1, (float4*)agg, n4);
        k_scatter_bn<<<4096, 256, 0, stream>>>(h1_fb, ei, scale1, shift1, agg, E);
        k_mlp_out<<<nblk, 256, 0, stream>>>(agg, W5a, b5a, W5b, b5b, out, gsum2, gsq2);
        k_bnfin<<<1, 64, 0, stream>>>(gsum2, gsq2, g5, be5, scale2, shift2, OUTF, 1.f / NN);
        k_bn_apply2<<<(NN * OUTF + 255) / 256, 256, 0, stream>>>(out, scale2, shift2, NN * OUTF);
    }
}